// Round 16
// baseline (224.672 us; speedup 1.0000x reference)
//
#include <hip/hip_runtime.h>

#define NB 2000          // N_BANDS
#define BATCH 8192
#define NT 500           // TARGET
#define NH1 50
#define NH2 10
#define HRc 1999.0f      // 1/h (uniform knots)
#define STEPc (1.0f/1999.0f)
#define LP 520           // LDS x pitch (ushorts): 1040B, 16B-aligned

typedef __attribute__((ext_vector_type(8))) short short8;   // 8 bf16 (4 VGPR)
typedef __attribute__((ext_vector_type(4))) float f32x4;    // MFMA acc

// ---- dtype helpers: flag==1 -> bf16 storage, flag==0 -> float32 ----
__device__ __forceinline__ float b2f(unsigned short u) {
    return __uint_as_float(((unsigned int)u) << 16);
}
__device__ __forceinline__ unsigned short f2b(float f) {
    unsigned int u = __float_as_uint(f);
    return (unsigned short)((u + 0x7FFFu + ((u >> 16) & 1u)) >> 16);
}
__device__ __forceinline__ float ldv(const void* p, int i, int flag) {
    return flag ? b2f(((const unsigned short*)p)[i]) : ((const float*)p)[i];
}
// In-wave dtype detect (proven R12): byte[4k+1] of f32 uniform(0,1) is
// mantissa (~75% > 0x3F); for bf16 it's sign+exp[7:1] <= 0x3F always.
__device__ __forceinline__ int wave_detect(const void* x) {
    const unsigned char* xb = (const unsigned char*)x;
    int lane = threadIdx.x & 63;
    int pred = xb[4 * lane + 1] > 0x3F;
    unsigned long long m = __ballot(pred);
    return (__popcll(m) > 4) ? 0 : 1;   // 0 = float32, 1 = bf16
}

// =====================================================================
// P1 standalone (proven R9-R17, verbatim).
// =====================================================================
__global__ __launch_bounds__(64, 1) void p1_stencil(
        const void* __restrict__ xdet, const void* __restrict__ raw_index,
        float* __restrict__ S_coef, int* __restrict__ S_base) {
    __shared__ float cp_tab[64];
    __shared__ float sc[2];
    int tid = threadIdx.x;
    int flag = wave_detect(xdet);
    if (tid == 0) {
        double cp = 0.5;
        cp_tab[0] = 0.5f;
        for (int i = 1; i < 64; ++i) { cp = 1.0 / (4.0 - cp); cp_tab[i] = (float)cp; }
        sc[0] = (float)cp;
        sc[1] = (float)(1.0 / (2.0 - cp));
    }
    __syncthreads();
    int t = blockIdx.x * 64 + tid;
    if (t >= NT) return;
    float c_inf = sc[0], w_last = sc[1];

    float coef_rel[34];
    #pragma unroll
    for (int k = 0; k < 34; ++k) coef_rel[k] = 0.0f;

    float r = ldv(raw_index, t, flag);
    float v = 1.0f / (1.0f + expf(-r));
    int lo = 0, hi = NB;
    while (lo < hi) {
        int mid = (lo + hi) >> 1;
        float tm = (float)mid * STEPc;
        if (tm < v) lo = mid + 1; else hi = mid;
    }
    int idx = lo - 1;
    idx = idx < 0 ? 0 : (idx > NB - 2 ? NB - 2 : idx);
    float f = v - (float)idx * STEPc;
    float u = f * HRc;
    float A = 1.0f + u * u * (2.0f * u - 3.0f);
    float B = u * u * (3.0f - 2.0f * u);
    float C = f * (1.0f - u) * (1.0f - u);
    float D = f * u * (u - 1.0f);

    const float g3 = 3.0f * HRc * HRc;
    const float invhr = 1.0f / HRc;

    #pragma unroll
    for (int row = 0; row < 2; ++row) {
        int j = idx + row;
        float scale = row ? D : C;
        float z[35];
        #pragma unroll
        for (int q = 0; q < 35; ++q) z[q] = 0.0f;
        float w0 = (j <= NB - 2) ? ((j < 64) ? cp_tab[j] : c_inf) : w_last;
        z[17] = w0 * invhr;
        #pragma unroll
        for (int s = 1; s <= 17; ++s) {
            int m = j + s;
            float wm;
            if (m <= NB - 2)      wm = (m < 64) ? cp_tab[m] : c_inf;
            else if (m == NB - 1) wm = w_last;
            else                  wm = 0.0f;
            z[17 + s] = -wm * z[17 + s - 1];
        }
        #pragma unroll
        for (int s = 16; s >= -17; --s) {
            int m = j + s;
            float cpv;
            if (m >= NB - 1 || m < 0) cpv = 0.0f;
            else                      cpv = (m < 64) ? cp_tab[m] : c_inf;
            z[17 + s] = z[17 + s] - cpv * z[17 + s + 1];
        }
        #pragma unroll
        for (int s = -16; s <= 16; ++s) {
            int m = j + s;
            float gv = 0.0f;
            if (m >= 1)      gv += z[17 + s - 1];
            if (m <= NB - 2) gv -= z[17 + s + 1];
            if (m == NB - 1) gv += z[17 + s];
            if (m == 0)      gv -= z[17 + s];
            gv *= g3;
            bool valid = (m >= 0) && (m <= NB - 1);
            coef_rel[s + row + 16] += valid ? scale * gv : 0.0f;
        }
    }
    coef_rel[16] += A;
    coef_rel[17] += B;

    #pragma unroll
    for (int j = 0; j < 34; ++j) S_coef[t * 34 + j] = coef_rel[j];
    S_base[t] = idx;
}

// =====================================================================
// M-BUILD2 (R22, passed R15: gather off the top-5 at 16+ waves/CU).
// =====================================================================
__global__ __launch_bounds__(256) void m_build2(
        const void* __restrict__ xdet, const void* __restrict__ W1,
        const float* __restrict__ S_coef, const int* __restrict__ S_base,
        unsigned int* __restrict__ MB) {
    __shared__ int sb[NT];
    __shared__ float red0[4][64];
    __shared__ float red1[4][64];
    int tid = threadIdx.x;
    int flag = wave_detect(xdet);
    for (int i = tid; i < NT; i += 256) sb[i] = S_base[i];
    __syncthreads();
    int wv = tid >> 6;                       // wave 0..3: t-range owner
    int h = tid & 63;
    int hh = h < NH1 ? h : NH1 - 1;
    int k2 = blockIdx.x;                     // 0..1023, one k2 per block
    int k0 = 2 * k2;                         // even, <= 2046
    float acc0 = 0.0f, acc1 = 0.0f;
    if (k0 < NB) {
        int t0 = wv * 125, t1 = t0 + 125;    // 4 x 125 = 500
        #pragma unroll 4
        for (int t = t0; t < t1; ++t) {
            int idx = sb[t];                 // LDS broadcast
            int rel0 = k0 - idx + 16;
            if (rel0 >= -1 && rel0 < 34) {   // wave-uniform (hit region)
                float w1v = ldv(W1, t * NH1 + hh, flag);
                if (rel0 >= 0)  acc0 += S_coef[t * 34 + rel0] * w1v;
                if (rel0 < 33)  acc1 += S_coef[t * 34 + rel0 + 1] * w1v;
            }
        }
    }
    red0[wv][h] = acc0;
    red1[wv][h] = acc1;
    __syncthreads();
    if (tid < 64) {                          // h = tid; fixed reduce order
        float a0 = ((red0[0][tid] + red0[1][tid]) + red0[2][tid]) + red0[3][tid];
        float a1 = ((red1[0][tid] + red1[1][tid]) + red1[2][tid]) + red1[3][tid];
        int hh2 = tid;                       // lane==h here
        bool ok = (hh2 < NH1) && (k0 < NB);
        unsigned int lo16 = ok ? (unsigned int)f2b(a0) : 0u;
        unsigned int hi16 = ok ? (unsigned int)f2b(a1) : 0u;
        int kt = k0 >> 5;                    // 0..63
        int kr = k0 & 31;
        int gg = kr >> 3;                    // k-slot group 0..3
        int j  = kr & 7;                     // even: 0,2,4,6
        int ht = hh2 >> 4;                   // h-tile 0..3
        int lt = gg * 16 + (hh2 & 15);       // target lane
        MB[(((kt * 4 + ht) * 64 + lt) << 2) + (j >> 1)] = lo16 | (hi16 << 16);
    }
}

// =====================================================================
// G-FUSED (R21, passed R14/R15): R17 structure + deep prefetch on the
// bf16 path. R23 is a MEASUREMENT round: kernel_launch dispatches it
// 5x (idempotent) => T = 136.75 + 4*(g_warm + gap). Resolves whether
// deep prefetch worked (g ~ 10-15) or not (g ~ 25-40).
// =====================================================================
__global__ __launch_bounds__(512, 4) void g_fused(
        const void* __restrict__ x, const unsigned int* __restrict__ MB,
        const void* __restrict__ b1, const void* __restrict__ W2,
        const void* __restrict__ b2, const void* __restrict__ W3,
        const void* __restrict__ b3, void* __restrict__ out) {
    __shared__ __align__(16) unsigned short lx[2][16 * LP];  // 33.3 KB
    __shared__ float red[8][16][68];                         // 34.8 KB
    __shared__ float Wmlp[NH1 * NH2 + NH1 + NH2 + NH2 + 1];  // 571

    int tid = threadIdx.x;
    int flag = wave_detect(x);

    for (int i = tid; i < NH1 * NH2; i += 512) Wmlp[i] = ldv(W2, i, flag);
    if (tid < NH1) Wmlp[500 + tid] = ldv(b1, tid, flag);
    if (tid < NH2) Wmlp[550 + tid] = ldv(b2, tid, flag);
    if (tid < NH2) Wmlp[560 + tid] = ldv(W3, tid, flag);
    if (tid == 0)  Wmlp[570] = ldv(b3, 0, flag);

    int lane = tid & 63;
    int c16  = tid & 15;         // A row offset / C col
    int g    = (tid >> 4) & 3;   // k-slot group 0..3
    int w    = tid >> 6;         // wave 0..7
    int srow = tid >> 5;         // staging row 0..15
    int soff = tid & 31;         // 16B slot within row-half
    int r0   = blockIdx.x * 16;
    const unsigned short* xs = (const unsigned short*)x;
    const float*          xf = (const float*)x;
    size_t crow = (size_t)(r0 + srow) * NB;

    f32x4 acc[4];
    #pragma unroll
    for (int ht = 0; ht < 4; ++ht) acc[ht] = (f32x4){0.f, 0.f, 0.f, 0.f};

    union AU { uint4 u; short8 s; };
    const uint4* mb4 = (const uint4*)MB;

    if (flag) {
        // ============== bf16 path: 8 loads all in flight ==============
        uint4 pf[8];
        #pragma unroll
        for (int c = 0; c < 4; ++c) {
            int gk0 = c * 512 + soff * 8;
            int gk1 = gk0 + 256;
            pf[2 * c]     = (gk0 + 8 <= NB) ? *(const uint4*)(xs + crow + gk0)
                                            : make_uint4(0u, 0u, 0u, 0u);
            pf[2 * c + 1] = (gk1 + 8 <= NB) ? *(const uint4*)(xs + crow + gk1)
                                            : make_uint4(0u, 0u, 0u, 0u);
        }
        // prologue: chunk 0 -> lx[0]
        *(uint4*)&lx[0][srow * LP + soff * 8]       = pf[0];
        *(uint4*)&lx[0][srow * LP + soff * 8 + 256] = pf[1];

        int cur = 0;
        #pragma unroll
        for (int c = 0; c < 4; ++c) {
            __syncthreads();   // staged buf[cur] ready
            #pragma unroll
            for (int dk = 0; dk < 2; ++dk) {
                int ktl = 2 * w + dk;
                AU a;
                a.u = *(const uint4*)&lx[cur][c16 * LP + ktl * 32 + g * 8];
                int kt = c * 16 + ktl;
                #pragma unroll
                for (int ht = 0; ht < 4; ++ht) {
                    AU b; b.u = mb4[(kt * 4 + ht) * 64 + lane];
                    acc[ht] = __builtin_amdgcn_mfma_f32_16x16x32_bf16(a.s, b.s, acc[ht], 0, 0, 0);
                }
            }
            if (c < 3) {       // write-late: next chunk from prefetch regs
                *(uint4*)&lx[cur ^ 1][srow * LP + soff * 8]       = pf[2 * (c + 1)];
                *(uint4*)&lx[cur ^ 1][srow * LP + soff * 8 + 256] = pf[2 * (c + 1) + 1];
            }
            __syncthreads();
            cur ^= 1;
        }
    } else {
        // ===== f32 path: proven R17 per-chunk issue-early flow =====
        #define LDSEGF(dst, gk) do {                                          \
            int _gk = (gk);                                                   \
            if (_gk + 8 <= NB) {                                              \
                float4 _v0 = *(const float4*)(xf + crow + _gk);               \
                float4 _v1 = *(const float4*)(xf + crow + _gk + 4);           \
                (dst).x = (unsigned)f2b(_v0.x) | ((unsigned)f2b(_v0.y) << 16); \
                (dst).y = (unsigned)f2b(_v0.z) | ((unsigned)f2b(_v0.w) << 16); \
                (dst).z = (unsigned)f2b(_v1.x) | ((unsigned)f2b(_v1.y) << 16); \
                (dst).w = (unsigned)f2b(_v1.z) | ((unsigned)f2b(_v1.w) << 16); \
            } else {                                                          \
                (dst) = make_uint4(0u, 0u, 0u, 0u);                           \
            }                                                                 \
        } while (0)
        {
            uint4 p0, p1;
            LDSEGF(p0, soff * 8);
            LDSEGF(p1, soff * 8 + 256);
            *(uint4*)&lx[0][srow * LP + soff * 8]       = p0;
            *(uint4*)&lx[0][srow * LP + soff * 8 + 256] = p1;
        }
        int cur = 0;
        #pragma unroll
        for (int c = 0; c < 4; ++c) {
            __syncthreads();
            uint4 s0 = make_uint4(0u,0u,0u,0u), s1 = make_uint4(0u,0u,0u,0u);
            if (c < 3) {
                LDSEGF(s0, (c + 1) * 512 + soff * 8);
                LDSEGF(s1, (c + 1) * 512 + soff * 8 + 256);
            }
            #pragma unroll
            for (int dk = 0; dk < 2; ++dk) {
                int ktl = 2 * w + dk;
                AU a;
                a.u = *(const uint4*)&lx[cur][c16 * LP + ktl * 32 + g * 8];
                int kt = c * 16 + ktl;
                #pragma unroll
                for (int ht = 0; ht < 4; ++ht) {
                    AU b; b.u = mb4[(kt * 4 + ht) * 64 + lane];
                    acc[ht] = __builtin_amdgcn_mfma_f32_16x16x32_bf16(a.s, b.s, acc[ht], 0, 0, 0);
                }
            }
            if (c < 3) {
                *(uint4*)&lx[cur ^ 1][srow * LP + soff * 8]       = s0;
                *(uint4*)&lx[cur ^ 1][srow * LP + soff * 8 + 256] = s1;
            }
            __syncthreads();
            cur ^= 1;
        }
        #undef LDSEGF
    }

    // partials: C layout col = c16, row = g*4 + reg
    #pragma unroll
    for (int ht = 0; ht < 4; ++ht)
        #pragma unroll
        for (int r = 0; r < 4; ++r)
            red[w][g * 4 + r][ht * 16 + c16] = acc[ht][r];
    __syncthreads();

    // reduce 8 partials: 1024 cells, 512 threads x 2
    #pragma unroll
    for (int ii = 0; ii < 2; ++ii) {
        int idx = tid + ii * 512;
        int row = idx >> 6, h = idx & 63;
        float s = 0.0f;
        #pragma unroll
        for (int w2 = 0; w2 < 8; ++w2) s += red[w2][row][h];
        red[0][row][h] = s;
    }
    __syncthreads();

    if (tid < 16) {
        float h1v[NH1];
        #pragma unroll
        for (int h = 0; h < NH1; ++h) {
            float vv = red[0][tid][h] + Wmlp[500 + h];
            h1v[h] = vv >= 0.0f ? vv : 0.01f * vv;
        }
        float o = Wmlp[570];
        for (int j = 0; j < NH2; ++j) {
            float a2 = Wmlp[550 + j];
            #pragma unroll
            for (int h = 0; h < NH1; ++h)
                a2 = fmaf(h1v[h], Wmlp[h * NH2 + j], a2);
            a2 = a2 >= 0.0f ? a2 : 0.01f * a2;
            o = fmaf(a2, Wmlp[560 + j], o);
        }
        int b = r0 + tid;
        if (flag) ((unsigned short*)out)[b] = f2b(o);
        else      ((float*)out)[b] = o;
    }
}

extern "C" void kernel_launch(void* const* d_in, const int* in_sizes, int n_in,
                              void* d_out, int out_size, void* d_ws, size_t ws_size,
                              hipStream_t stream) {
    const void* x   = d_in[0];
    const void* raw = d_in[1];
    const void* W1  = d_in[2];
    const void* b1  = d_in[3];
    const void* W2  = d_in[4];
    const void* b2  = d_in[5];
    const void* W3  = d_in[6];
    const void* b3  = d_in[7];

    // Workspace: S_base 512 i32 | S_coef 17000 f32 | MB 65536 u32.
    float* w      = (float*)d_ws;
    int*   S_base = (int*)w;                        // 512 ints
    float* S_coef = w + 512;                        // 17000 floats
    unsigned int* MB = (unsigned int*)(w + 17512);  // 65536 uints, 16B-aligned

    p1_stencil<<<8, 64, 0, stream>>>(x, raw, S_coef, S_base);
    m_build2<<<1024, 256, 0, stream>>>(x, W1, S_coef, S_base, MB);
    // R23 MEASUREMENT: g_fused is idempotent; 5 launches =>
    // T = 136.75 + 4*(g_warm + gap). g+gap <= 16 => g at floor (declare
    // next round); g+gap >= 20 => restage g via global_load_lds.
    g_fused<<<512, 512, 0, stream>>>(x, MB, b1, W2, b2, W3, b3, d_out);
    g_fused<<<512, 512, 0, stream>>>(x, MB, b1, W2, b2, W3, b3, d_out);
    g_fused<<<512, 512, 0, stream>>>(x, MB, b1, W2, b2, W3, b3, d_out);
    g_fused<<<512, 512, 0, stream>>>(x, MB, b1, W2, b2, W3, b3, d_out);
    g_fused<<<512, 512, 0, stream>>>(x, MB, b1, W2, b2, W3, b3, d_out);
}

// Round 17
// 176.633 us; speedup vs baseline: 1.2720x; 1.2720x over previous
//
#include <hip/hip_runtime.h>

#define NB 2000          // N_BANDS
#define BATCH 8192
#define NT 500           // TARGET
#define NH1 50
#define NH2 10
#define HRc 1999.0f      // 1/h (uniform knots)
#define STEPc (1.0f/1999.0f)
#define LP 520           // LDS x pitch (ushorts): 1040B, 16B-aligned

typedef __attribute__((ext_vector_type(8))) short short8;   // 8 bf16 (4 VGPR)
typedef __attribute__((ext_vector_type(4))) float f32x4;    // MFMA acc

// ---- dtype helpers: flag==1 -> bf16 storage, flag==0 -> float32 ----
__device__ __forceinline__ float b2f(unsigned short u) {
    return __uint_as_float(((unsigned int)u) << 16);
}
__device__ __forceinline__ unsigned short f2b(float f) {
    unsigned int u = __float_as_uint(f);
    return (unsigned short)((u + 0x7FFFu + ((u >> 16) & 1u)) >> 16);
}
__device__ __forceinline__ float ldv(const void* p, int i, int flag) {
    return flag ? b2f(((const unsigned short*)p)[i]) : ((const float*)p)[i];
}
// In-wave dtype detect (proven R12): byte[4k+1] of f32 uniform(0,1) is
// mantissa (~75% > 0x3F); for bf16 it's sign+exp[7:1] <= 0x3F always.
__device__ __forceinline__ int wave_detect(const void* x) {
    const unsigned char* xb = (const unsigned char*)x;
    int lane = threadIdx.x & 63;
    int pred = xb[4 * lane + 1] > 0x3F;
    unsigned long long m = __ballot(pred);
    return (__popcll(m) > 4) ? 0 : 1;   // 0 = float32, 1 = bf16
}

// =====================================================================
// M-BUILD3 (R24): p1 merged into the gather WITHOUT grid.sync and
// WITHOUT the 70KB-LDS occupancy loss that killed R21's pm_build.
// Evidence: 5 structural variants of g all ~20us (dispatch overhead,
// not memory); so the lever is dispatch count. For block k2 a hit t
// needs only coef_rel[rel0], coef_rel[rel0+1] => recompute ON DEMAND:
//   Phase A: idx[t], v[t] for all 500 t (binary search VERBATIM).
//   Phase B: m_build2's 4x125 scan; on hit, z-chain (p1 VERBATIM,
//     static regs), stash z -> per-wave LDS (dynamic-index reads),
//     assemble the 2 entries with p1's exact op order and guards.
// Bit-identical MB: z-chain identical per (row,idx); per-entry
// accumulation order (row0 -> row1 -> A/B) and valid?x:0 adds
// preserved. LDS ~7KB => 8+ waves/CU; ~4-9 hits/wave ~1-2us extra.
// =====================================================================
__global__ __launch_bounds__(256) void m_build3(
        const void* __restrict__ x, const void* __restrict__ raw_index,
        const void* __restrict__ W1, unsigned int* __restrict__ MB) {
    __shared__ int   sbS[NT];
    __shared__ float vS[NT];
    __shared__ float red0[4][64];
    __shared__ float red1[4][64];
    __shared__ float zW[4][40];          // per-wave z stash (35 used)
    __shared__ float cp_tab[64];
    __shared__ float sc[2];

    int tid = threadIdx.x;
    int flag = wave_detect(x);
    if (tid == 0) {
        double cp = 0.5;
        cp_tab[0] = 0.5f;
        for (int i = 1; i < 64; ++i) { cp = 1.0 / (4.0 - cp); cp_tab[i] = (float)cp; }
        sc[0] = (float)cp;
        sc[1] = (float)(1.0 / (2.0 - cp));
    }
    __syncthreads();
    float c_inf = sc[0], w_last = sc[1];

    // ---- Phase A: idx + v for all t (binary search verbatim) ----
    for (int rep = 0; rep < 2; ++rep) {
        int t = tid + rep * 256;
        if (t < NT) {
            float r = ldv(raw_index, t, flag);
            float v = 1.0f / (1.0f + expf(-r));
            int lo = 0, hi = NB;
            while (lo < hi) {
                int mid = (lo + hi) >> 1;
                float tm = (float)mid * STEPc;
                if (tm < v) lo = mid + 1; else hi = mid;
            }
            int idx = lo - 1;
            idx = idx < 0 ? 0 : (idx > NB - 2 ? NB - 2 : idx);
            sbS[t] = idx;
            vS[t]  = v;
        }
    }
    __syncthreads();

    // ---- Phase B: gather with on-demand stencil ----
    int wv = tid >> 6;                   // wave 0..3: t-range owner
    int h = tid & 63;
    int hh = h < NH1 ? h : NH1 - 1;
    int k2 = blockIdx.x;                 // one k2 per block
    int k0 = 2 * k2;                     // even, <= 2046
    const float g3 = 3.0f * HRc * HRc;
    const float invhr = 1.0f / HRc;
    float acc0 = 0.0f, acc1 = 0.0f;
    if (k0 < NB) {
        int t0 = wv * 125, t1 = t0 + 125;
        for (int t = t0; t < t1; ++t) {
            int idx = sbS[t];            // LDS broadcast
            int rel0 = k0 - idx + 16;
            if (rel0 >= -1 && rel0 < 34) {   // wave-uniform hit
                float v = vS[t];
                float f = v - (float)idx * STEPc;
                float u = f * HRc;
                float A = 1.0f + u * u * (2.0f * u - 3.0f);
                float B = u * u * (3.0f - 2.0f * u);
                float C = f * (1.0f - u) * (1.0f - u);
                float D = f * u * (u - 1.0f);

                float c0 = 0.0f, c1 = 0.0f;
                #pragma unroll
                for (int row = 0; row < 2; ++row) {
                    int j = idx + row;
                    float scale = row ? D : C;
                    float z[35];
                    #pragma unroll
                    for (int q = 0; q < 35; ++q) z[q] = 0.0f;
                    float w0 = (j <= NB - 2) ? ((j < 64) ? cp_tab[j] : c_inf) : w_last;
                    z[17] = w0 * invhr;
                    #pragma unroll
                    for (int s = 1; s <= 17; ++s) {
                        int m = j + s;
                        float wm;
                        if (m <= NB - 2)      wm = (m < 64) ? cp_tab[m] : c_inf;
                        else if (m == NB - 1) wm = w_last;
                        else                  wm = 0.0f;
                        z[17 + s] = -wm * z[17 + s - 1];
                    }
                    #pragma unroll
                    for (int s = 16; s >= -17; --s) {
                        int m = j + s;
                        float cpv;
                        if (m >= NB - 1 || m < 0) cpv = 0.0f;
                        else                      cpv = (m < 64) ? cp_tab[m] : c_inf;
                        z[17 + s] = z[17 + s] - cpv * z[17 + s + 1];
                    }
                    // stash z (all lanes same values; same-addr writes benign)
                    #pragma unroll
                    for (int q = 0; q < 35; ++q) zW[wv][q] = z[q];

                    // contribution to c0 = coef_rel[rel0] (p1 op order)
                    {
                        int s0 = rel0 - 16 - row;
                        if (rel0 >= 0 && s0 >= -16 && s0 <= 16) {
                            int m = j + s0;
                            float gv = 0.0f;
                            if (m >= 1)      gv += zW[wv][17 + s0 - 1];
                            if (m <= NB - 2) gv -= zW[wv][17 + s0 + 1];
                            if (m == NB - 1) gv += zW[wv][17 + s0];
                            if (m == 0)      gv -= zW[wv][17 + s0];
                            gv *= g3;
                            bool valid = (m >= 0) && (m <= NB - 1);
                            c0 += valid ? scale * gv : 0.0f;
                        }
                        int s1 = s0 + 1;   // for coef_rel[rel0+1]
                        if (rel0 < 33 && s1 >= -16 && s1 <= 16) {
                            int m = j + s1;
                            float gv = 0.0f;
                            if (m >= 1)      gv += zW[wv][17 + s1 - 1];
                            if (m <= NB - 2) gv -= zW[wv][17 + s1 + 1];
                            if (m == NB - 1) gv += zW[wv][17 + s1];
                            if (m == 0)      gv -= zW[wv][17 + s1];
                            gv *= g3;
                            bool valid = (m >= 0) && (m <= NB - 1);
                            c1 += valid ? scale * gv : 0.0f;
                        }
                    }
                }
                if (rel0 == 16)     c0 += A;
                if (rel0 == 17)     c0 += B;
                if (rel0 + 1 == 16) c1 += A;
                if (rel0 + 1 == 17) c1 += B;

                float w1v = ldv(W1, t * NH1 + hh, flag);
                if (rel0 >= 0)  acc0 += c0 * w1v;
                if (rel0 < 33)  acc1 += c1 * w1v;
            }
        }
    }
    red0[wv][h] = acc0;
    red1[wv][h] = acc1;
    __syncthreads();
    if (tid < 64) {                      // h = tid; fixed reduce order
        float a0 = ((red0[0][tid] + red0[1][tid]) + red0[2][tid]) + red0[3][tid];
        float a1 = ((red1[0][tid] + red1[1][tid]) + red1[2][tid]) + red1[3][tid];
        int hh2 = tid;
        bool ok = (hh2 < NH1) && (k0 < NB);
        unsigned int lo16 = ok ? (unsigned int)f2b(a0) : 0u;
        unsigned int hi16 = ok ? (unsigned int)f2b(a1) : 0u;
        int kt = k0 >> 5;
        int kr = k0 & 31;
        int gg = kr >> 3;
        int j  = kr & 7;
        int ht = hh2 >> 4;
        int lt = gg * 16 + (hh2 & 15);
        MB[(((kt * 4 + ht) * 64 + lt) << 2) + (j >> 1)] = lo16 | (hi16 << 16);
    }
}

// =====================================================================
// G-FUSED (R21, passed R14/R15/R16): R17 structure + deep prefetch on
// the bf16 path. Verbatim.
// =====================================================================
__global__ __launch_bounds__(512, 4) void g_fused(
        const void* __restrict__ x, const unsigned int* __restrict__ MB,
        const void* __restrict__ b1, const void* __restrict__ W2,
        const void* __restrict__ b2, const void* __restrict__ W3,
        const void* __restrict__ b3, void* __restrict__ out) {
    __shared__ __align__(16) unsigned short lx[2][16 * LP];  // 33.3 KB
    __shared__ float red[8][16][68];                         // 34.8 KB
    __shared__ float Wmlp[NH1 * NH2 + NH1 + NH2 + NH2 + 1];  // 571

    int tid = threadIdx.x;
    int flag = wave_detect(x);

    for (int i = tid; i < NH1 * NH2; i += 512) Wmlp[i] = ldv(W2, i, flag);
    if (tid < NH1) Wmlp[500 + tid] = ldv(b1, tid, flag);
    if (tid < NH2) Wmlp[550 + tid] = ldv(b2, tid, flag);
    if (tid < NH2) Wmlp[560 + tid] = ldv(W3, tid, flag);
    if (tid == 0)  Wmlp[570] = ldv(b3, 0, flag);

    int lane = tid & 63;
    int c16  = tid & 15;         // A row offset / C col
    int g    = (tid >> 4) & 3;   // k-slot group 0..3
    int w    = tid >> 6;         // wave 0..7
    int srow = tid >> 5;         // staging row 0..15
    int soff = tid & 31;         // 16B slot within row-half
    int r0   = blockIdx.x * 16;
    const unsigned short* xs = (const unsigned short*)x;
    const float*          xf = (const float*)x;
    size_t crow = (size_t)(r0 + srow) * NB;

    f32x4 acc[4];
    #pragma unroll
    for (int ht = 0; ht < 4; ++ht) acc[ht] = (f32x4){0.f, 0.f, 0.f, 0.f};

    union AU { uint4 u; short8 s; };
    const uint4* mb4 = (const uint4*)MB;

    if (flag) {
        // ============== bf16 path: 8 loads all in flight ==============
        uint4 pf[8];
        #pragma unroll
        for (int c = 0; c < 4; ++c) {
            int gk0 = c * 512 + soff * 8;
            int gk1 = gk0 + 256;
            pf[2 * c]     = (gk0 + 8 <= NB) ? *(const uint4*)(xs + crow + gk0)
                                            : make_uint4(0u, 0u, 0u, 0u);
            pf[2 * c + 1] = (gk1 + 8 <= NB) ? *(const uint4*)(xs + crow + gk1)
                                            : make_uint4(0u, 0u, 0u, 0u);
        }
        // prologue: chunk 0 -> lx[0]
        *(uint4*)&lx[0][srow * LP + soff * 8]       = pf[0];
        *(uint4*)&lx[0][srow * LP + soff * 8 + 256] = pf[1];

        int cur = 0;
        #pragma unroll
        for (int c = 0; c < 4; ++c) {
            __syncthreads();   // staged buf[cur] ready
            #pragma unroll
            for (int dk = 0; dk < 2; ++dk) {
                int ktl = 2 * w + dk;
                AU a;
                a.u = *(const uint4*)&lx[cur][c16 * LP + ktl * 32 + g * 8];
                int kt = c * 16 + ktl;
                #pragma unroll
                for (int ht = 0; ht < 4; ++ht) {
                    AU b; b.u = mb4[(kt * 4 + ht) * 64 + lane];
                    acc[ht] = __builtin_amdgcn_mfma_f32_16x16x32_bf16(a.s, b.s, acc[ht], 0, 0, 0);
                }
            }
            if (c < 3) {       // write-late: next chunk from prefetch regs
                *(uint4*)&lx[cur ^ 1][srow * LP + soff * 8]       = pf[2 * (c + 1)];
                *(uint4*)&lx[cur ^ 1][srow * LP + soff * 8 + 256] = pf[2 * (c + 1) + 1];
            }
            __syncthreads();
            cur ^= 1;
        }
    } else {
        // ===== f32 path: proven R17 per-chunk issue-early flow =====
        #define LDSEGF(dst, gk) do {                                          \
            int _gk = (gk);                                                   \
            if (_gk + 8 <= NB) {                                              \
                float4 _v0 = *(const float4*)(xf + crow + _gk);               \
                float4 _v1 = *(const float4*)(xf + crow + _gk + 4);           \
                (dst).x = (unsigned)f2b(_v0.x) | ((unsigned)f2b(_v0.y) << 16); \
                (dst).y = (unsigned)f2b(_v0.z) | ((unsigned)f2b(_v0.w) << 16); \
                (dst).z = (unsigned)f2b(_v1.x) | ((unsigned)f2b(_v1.y) << 16); \
                (dst).w = (unsigned)f2b(_v1.z) | ((unsigned)f2b(_v1.w) << 16); \
            } else {                                                          \
                (dst) = make_uint4(0u, 0u, 0u, 0u);                           \
            }                                                                 \
        } while (0)
        {
            uint4 p0, p1;
            LDSEGF(p0, soff * 8);
            LDSEGF(p1, soff * 8 + 256);
            *(uint4*)&lx[0][srow * LP + soff * 8]       = p0;
            *(uint4*)&lx[0][srow * LP + soff * 8 + 256] = p1;
        }
        int cur = 0;
        #pragma unroll
        for (int c = 0; c < 4; ++c) {
            __syncthreads();
            uint4 s0 = make_uint4(0u,0u,0u,0u), s1 = make_uint4(0u,0u,0u,0u);
            if (c < 3) {
                LDSEGF(s0, (c + 1) * 512 + soff * 8);
                LDSEGF(s1, (c + 1) * 512 + soff * 8 + 256);
            }
            #pragma unroll
            for (int dk = 0; dk < 2; ++dk) {
                int ktl = 2 * w + dk;
                AU a;
                a.u = *(const uint4*)&lx[cur][c16 * LP + ktl * 32 + g * 8];
                int kt = c * 16 + ktl;
                #pragma unroll
                for (int ht = 0; ht < 4; ++ht) {
                    AU b; b.u = mb4[(kt * 4 + ht) * 64 + lane];
                    acc[ht] = __builtin_amdgcn_mfma_f32_16x16x32_bf16(a.s, b.s, acc[ht], 0, 0, 0);
                }
            }
            if (c < 3) {
                *(uint4*)&lx[cur ^ 1][srow * LP + soff * 8]       = s0;
                *(uint4*)&lx[cur ^ 1][srow * LP + soff * 8 + 256] = s1;
            }
            __syncthreads();
            cur ^= 1;
        }
        #undef LDSEGF
    }

    // partials: C layout col = c16, row = g*4 + reg
    #pragma unroll
    for (int ht = 0; ht < 4; ++ht)
        #pragma unroll
        for (int r = 0; r < 4; ++r)
            red[w][g * 4 + r][ht * 16 + c16] = acc[ht][r];
    __syncthreads();

    // reduce 8 partials: 1024 cells, 512 threads x 2
    #pragma unroll
    for (int ii = 0; ii < 2; ++ii) {
        int idx = tid + ii * 512;
        int row = idx >> 6, h = idx & 63;
        float s = 0.0f;
        #pragma unroll
        for (int w2 = 0; w2 < 8; ++w2) s += red[w2][row][h];
        red[0][row][h] = s;
    }
    __syncthreads();

    if (tid < 16) {
        float h1v[NH1];
        #pragma unroll
        for (int h = 0; h < NH1; ++h) {
            float vv = red[0][tid][h] + Wmlp[500 + h];
            h1v[h] = vv >= 0.0f ? vv : 0.01f * vv;
        }
        float o = Wmlp[570];
        for (int j = 0; j < NH2; ++j) {
            float a2 = Wmlp[550 + j];
            #pragma unroll
            for (int h = 0; h < NH1; ++h)
                a2 = fmaf(h1v[h], Wmlp[h * NH2 + j], a2);
            a2 = a2 >= 0.0f ? a2 : 0.01f * a2;
            o = fmaf(a2, Wmlp[560 + j], o);
        }
        int b = r0 + tid;
        if (flag) ((unsigned short*)out)[b] = f2b(o);
        else      ((float*)out)[b] = o;
    }
}

extern "C" void kernel_launch(void* const* d_in, const int* in_sizes, int n_in,
                              void* d_out, int out_size, void* d_ws, size_t ws_size,
                              hipStream_t stream) {
    const void* x   = d_in[0];
    const void* raw = d_in[1];
    const void* W1  = d_in[2];
    const void* b1  = d_in[3];
    const void* W2  = d_in[4];
    const void* b2  = d_in[5];
    const void* W3  = d_in[6];
    const void* b3  = d_in[7];

    // Workspace: MB 65536 u32 (same offset as before; S slots unused).
    // No atomics, no pre-zeroing; every MB dword written each launch
    // (m_build3 covers k2 0..1023 fully; zero-filled k>=NB, h>=50).
    float* w = (float*)d_ws;
    unsigned int* MB = (unsigned int*)(w + 17512);  // 65536 uints, 16B-aligned

    // R24: 2 dispatches (was 3) — p1 folded into the gather on demand.
    m_build3<<<1024, 256, 0, stream>>>(x, raw, W1, MB);
    g_fused<<<512, 512, 0, stream>>>(x, MB, b1, W2, b2, W3, b3, d_out);
}

// Round 18
// 137.009 us; speedup vs baseline: 1.6398x; 1.2892x over previous
//
#include <hip/hip_runtime.h>

#define NB 2000          // N_BANDS
#define BATCH 8192
#define NT 500           // TARGET
#define NH1 50
#define NH2 10
#define HRc 1999.0f      // 1/h (uniform knots)
#define STEPc (1.0f/1999.0f)
#define LP 520           // LDS x pitch (ushorts): 1040B, 16B-aligned

typedef __attribute__((ext_vector_type(8))) short short8;   // 8 bf16 (4 VGPR)
typedef __attribute__((ext_vector_type(4))) float f32x4;    // MFMA acc

// ---- dtype helpers: flag==1 -> bf16 storage, flag==0 -> float32 ----
__device__ __forceinline__ float b2f(unsigned short u) {
    return __uint_as_float(((unsigned int)u) << 16);
}
__device__ __forceinline__ unsigned short f2b(float f) {
    unsigned int u = __float_as_uint(f);
    return (unsigned short)((u + 0x7FFFu + ((u >> 16) & 1u)) >> 16);
}
__device__ __forceinline__ float ldv(const void* p, int i, int flag) {
    return flag ? b2f(((const unsigned short*)p)[i]) : ((const float*)p)[i];
}
// In-wave dtype detect (proven R12): byte[4k+1] of f32 uniform(0,1) is
// mantissa (~75% > 0x3F); for bf16 it's sign+exp[7:1] <= 0x3F always.
__device__ __forceinline__ int wave_detect(const void* x) {
    const unsigned char* xb = (const unsigned char*)x;
    int lane = threadIdx.x & 63;
    int pred = xb[4 * lane + 1] > 0x3F;
    unsigned long long m = __ballot(pred);
    return (__popcll(m) > 4) ? 0 : 1;   // 0 = float32, 1 = bf16
}

// =====================================================================
// P1 standalone (proven R9-R17, verbatim). R25 = revert to the R15
// 136.75us best after R24's on-demand-recompute merge was refuted
// (m_build3 79.5us: serial z-chain per hit, latency-naked).
// =====================================================================
__global__ __launch_bounds__(64, 1) void p1_stencil(
        const void* __restrict__ xdet, const void* __restrict__ raw_index,
        float* __restrict__ S_coef, int* __restrict__ S_base) {
    __shared__ float cp_tab[64];
    __shared__ float sc[2];
    int tid = threadIdx.x;
    int flag = wave_detect(xdet);
    if (tid == 0) {
        double cp = 0.5;
        cp_tab[0] = 0.5f;
        for (int i = 1; i < 64; ++i) { cp = 1.0 / (4.0 - cp); cp_tab[i] = (float)cp; }
        sc[0] = (float)cp;
        sc[1] = (float)(1.0 / (2.0 - cp));
    }
    __syncthreads();
    int t = blockIdx.x * 64 + tid;
    if (t >= NT) return;
    float c_inf = sc[0], w_last = sc[1];

    float coef_rel[34];
    #pragma unroll
    for (int k = 0; k < 34; ++k) coef_rel[k] = 0.0f;

    float r = ldv(raw_index, t, flag);
    float v = 1.0f / (1.0f + expf(-r));
    int lo = 0, hi = NB;
    while (lo < hi) {
        int mid = (lo + hi) >> 1;
        float tm = (float)mid * STEPc;
        if (tm < v) lo = mid + 1; else hi = mid;
    }
    int idx = lo - 1;
    idx = idx < 0 ? 0 : (idx > NB - 2 ? NB - 2 : idx);
    float f = v - (float)idx * STEPc;
    float u = f * HRc;
    float A = 1.0f + u * u * (2.0f * u - 3.0f);
    float B = u * u * (3.0f - 2.0f * u);
    float C = f * (1.0f - u) * (1.0f - u);
    float D = f * u * (u - 1.0f);

    const float g3 = 3.0f * HRc * HRc;
    const float invhr = 1.0f / HRc;

    #pragma unroll
    for (int row = 0; row < 2; ++row) {
        int j = idx + row;
        float scale = row ? D : C;
        float z[35];
        #pragma unroll
        for (int q = 0; q < 35; ++q) z[q] = 0.0f;
        float w0 = (j <= NB - 2) ? ((j < 64) ? cp_tab[j] : c_inf) : w_last;
        z[17] = w0 * invhr;
        #pragma unroll
        for (int s = 1; s <= 17; ++s) {
            int m = j + s;
            float wm;
            if (m <= NB - 2)      wm = (m < 64) ? cp_tab[m] : c_inf;
            else if (m == NB - 1) wm = w_last;
            else                  wm = 0.0f;
            z[17 + s] = -wm * z[17 + s - 1];
        }
        #pragma unroll
        for (int s = 16; s >= -17; --s) {
            int m = j + s;
            float cpv;
            if (m >= NB - 1 || m < 0) cpv = 0.0f;
            else                      cpv = (m < 64) ? cp_tab[m] : c_inf;
            z[17 + s] = z[17 + s] - cpv * z[17 + s + 1];
        }
        #pragma unroll
        for (int s = -16; s <= 16; ++s) {
            int m = j + s;
            float gv = 0.0f;
            if (m >= 1)      gv += z[17 + s - 1];
            if (m <= NB - 2) gv -= z[17 + s + 1];
            if (m == NB - 1) gv += z[17 + s];
            if (m == 0)      gv -= z[17 + s];
            gv *= g3;
            bool valid = (m >= 0) && (m <= NB - 1);
            coef_rel[s + row + 16] += valid ? scale * gv : 0.0f;
        }
    }
    coef_rel[16] += A;
    coef_rel[17] += B;

    #pragma unroll
    for (int j = 0; j < 34; ++j) S_coef[t * 34 + j] = coef_rel[j];
    S_base[t] = idx;
}

// =====================================================================
// M-BUILD2 (R22, passed R15: gather off the top-5 at 16+ waves/CU).
// =====================================================================
__global__ __launch_bounds__(256) void m_build2(
        const void* __restrict__ xdet, const void* __restrict__ W1,
        const float* __restrict__ S_coef, const int* __restrict__ S_base,
        unsigned int* __restrict__ MB) {
    __shared__ int sb[NT];
    __shared__ float red0[4][64];
    __shared__ float red1[4][64];
    int tid = threadIdx.x;
    int flag = wave_detect(xdet);
    for (int i = tid; i < NT; i += 256) sb[i] = S_base[i];
    __syncthreads();
    int wv = tid >> 6;                       // wave 0..3: t-range owner
    int h = tid & 63;
    int hh = h < NH1 ? h : NH1 - 1;
    int k2 = blockIdx.x;                     // 0..1023, one k2 per block
    int k0 = 2 * k2;                         // even, <= 2046
    float acc0 = 0.0f, acc1 = 0.0f;
    if (k0 < NB) {
        int t0 = wv * 125, t1 = t0 + 125;    // 4 x 125 = 500
        #pragma unroll 4
        for (int t = t0; t < t1; ++t) {
            int idx = sb[t];                 // LDS broadcast
            int rel0 = k0 - idx + 16;
            if (rel0 >= -1 && rel0 < 34) {   // wave-uniform (hit region)
                float w1v = ldv(W1, t * NH1 + hh, flag);
                if (rel0 >= 0)  acc0 += S_coef[t * 34 + rel0] * w1v;
                if (rel0 < 33)  acc1 += S_coef[t * 34 + rel0 + 1] * w1v;
            }
        }
    }
    red0[wv][h] = acc0;
    red1[wv][h] = acc1;
    __syncthreads();
    if (tid < 64) {                          // h = tid; fixed reduce order
        float a0 = ((red0[0][tid] + red0[1][tid]) + red0[2][tid]) + red0[3][tid];
        float a1 = ((red1[0][tid] + red1[1][tid]) + red1[2][tid]) + red1[3][tid];
        int hh2 = tid;                       // lane==h here
        bool ok = (hh2 < NH1) && (k0 < NB);
        unsigned int lo16 = ok ? (unsigned int)f2b(a0) : 0u;
        unsigned int hi16 = ok ? (unsigned int)f2b(a1) : 0u;
        int kt = k0 >> 5;                    // 0..63
        int kr = k0 & 31;
        int gg = kr >> 3;                    // k-slot group 0..3
        int j  = kr & 7;                     // even: 0,2,4,6
        int ht = hh2 >> 4;                   // h-tile 0..3
        int lt = gg * 16 + (hh2 & 15);       // target lane
        MB[(((kt * 4 + ht) * 64 + lt) << 2) + (j >> 1)] = lo16 | (hi16 << 16);
    }
}

// =====================================================================
// G-FUSED (R21, passed R14/R15/R16): R17 structure + deep prefetch on
// the bf16 path (all 8 staging loads in flight up-front). Verbatim.
// =====================================================================
__global__ __launch_bounds__(512, 4) void g_fused(
        const void* __restrict__ x, const unsigned int* __restrict__ MB,
        const void* __restrict__ b1, const void* __restrict__ W2,
        const void* __restrict__ b2, const void* __restrict__ W3,
        const void* __restrict__ b3, void* __restrict__ out) {
    __shared__ __align__(16) unsigned short lx[2][16 * LP];  // 33.3 KB
    __shared__ float red[8][16][68];                         // 34.8 KB
    __shared__ float Wmlp[NH1 * NH2 + NH1 + NH2 + NH2 + 1];  // 571

    int tid = threadIdx.x;
    int flag = wave_detect(x);

    for (int i = tid; i < NH1 * NH2; i += 512) Wmlp[i] = ldv(W2, i, flag);
    if (tid < NH1) Wmlp[500 + tid] = ldv(b1, tid, flag);
    if (tid < NH2) Wmlp[550 + tid] = ldv(b2, tid, flag);
    if (tid < NH2) Wmlp[560 + tid] = ldv(W3, tid, flag);
    if (tid == 0)  Wmlp[570] = ldv(b3, 0, flag);

    int lane = tid & 63;
    int c16  = tid & 15;         // A row offset / C col
    int g    = (tid >> 4) & 3;   // k-slot group 0..3
    int w    = tid >> 6;         // wave 0..7
    int srow = tid >> 5;         // staging row 0..15
    int soff = tid & 31;         // 16B slot within row-half
    int r0   = blockIdx.x * 16;
    const unsigned short* xs = (const unsigned short*)x;
    const float*          xf = (const float*)x;
    size_t crow = (size_t)(r0 + srow) * NB;

    f32x4 acc[4];
    #pragma unroll
    for (int ht = 0; ht < 4; ++ht) acc[ht] = (f32x4){0.f, 0.f, 0.f, 0.f};

    union AU { uint4 u; short8 s; };
    const uint4* mb4 = (const uint4*)MB;

    if (flag) {
        // ============== bf16 path: 8 loads all in flight ==============
        uint4 pf[8];
        #pragma unroll
        for (int c = 0; c < 4; ++c) {
            int gk0 = c * 512 + soff * 8;
            int gk1 = gk0 + 256;
            pf[2 * c]     = (gk0 + 8 <= NB) ? *(const uint4*)(xs + crow + gk0)
                                            : make_uint4(0u, 0u, 0u, 0u);
            pf[2 * c + 1] = (gk1 + 8 <= NB) ? *(const uint4*)(xs + crow + gk1)
                                            : make_uint4(0u, 0u, 0u, 0u);
        }
        // prologue: chunk 0 -> lx[0]
        *(uint4*)&lx[0][srow * LP + soff * 8]       = pf[0];
        *(uint4*)&lx[0][srow * LP + soff * 8 + 256] = pf[1];

        int cur = 0;
        #pragma unroll
        for (int c = 0; c < 4; ++c) {
            __syncthreads();   // staged buf[cur] ready
            #pragma unroll
            for (int dk = 0; dk < 2; ++dk) {
                int ktl = 2 * w + dk;
                AU a;
                a.u = *(const uint4*)&lx[cur][c16 * LP + ktl * 32 + g * 8];
                int kt = c * 16 + ktl;
                #pragma unroll
                for (int ht = 0; ht < 4; ++ht) {
                    AU b; b.u = mb4[(kt * 4 + ht) * 64 + lane];
                    acc[ht] = __builtin_amdgcn_mfma_f32_16x16x32_bf16(a.s, b.s, acc[ht], 0, 0, 0);
                }
            }
            if (c < 3) {       // write-late: next chunk from prefetch regs
                *(uint4*)&lx[cur ^ 1][srow * LP + soff * 8]       = pf[2 * (c + 1)];
                *(uint4*)&lx[cur ^ 1][srow * LP + soff * 8 + 256] = pf[2 * (c + 1) + 1];
            }
            __syncthreads();
            cur ^= 1;
        }
    } else {
        // ===== f32 path: proven R17 per-chunk issue-early flow =====
        #define LDSEGF(dst, gk) do {                                          \
            int _gk = (gk);                                                   \
            if (_gk + 8 <= NB) {                                              \
                float4 _v0 = *(const float4*)(xf + crow + _gk);               \
                float4 _v1 = *(const float4*)(xf + crow + _gk + 4);           \
                (dst).x = (unsigned)f2b(_v0.x) | ((unsigned)f2b(_v0.y) << 16); \
                (dst).y = (unsigned)f2b(_v0.z) | ((unsigned)f2b(_v0.w) << 16); \
                (dst).z = (unsigned)f2b(_v1.x) | ((unsigned)f2b(_v1.y) << 16); \
                (dst).w = (unsigned)f2b(_v1.z) | ((unsigned)f2b(_v1.w) << 16); \
            } else {                                                          \
                (dst) = make_uint4(0u, 0u, 0u, 0u);                           \
            }                                                                 \
        } while (0)
        {
            uint4 p0, p1;
            LDSEGF(p0, soff * 8);
            LDSEGF(p1, soff * 8 + 256);
            *(uint4*)&lx[0][srow * LP + soff * 8]       = p0;
            *(uint4*)&lx[0][srow * LP + soff * 8 + 256] = p1;
        }
        int cur = 0;
        #pragma unroll
        for (int c = 0; c < 4; ++c) {
            __syncthreads();
            uint4 s0 = make_uint4(0u,0u,0u,0u), s1 = make_uint4(0u,0u,0u,0u);
            if (c < 3) {
                LDSEGF(s0, (c + 1) * 512 + soff * 8);
                LDSEGF(s1, (c + 1) * 512 + soff * 8 + 256);
            }
            #pragma unroll
            for (int dk = 0; dk < 2; ++dk) {
                int ktl = 2 * w + dk;
                AU a;
                a.u = *(const uint4*)&lx[cur][c16 * LP + ktl * 32 + g * 8];
                int kt = c * 16 + ktl;
                #pragma unroll
                for (int ht = 0; ht < 4; ++ht) {
                    AU b; b.u = mb4[(kt * 4 + ht) * 64 + lane];
                    acc[ht] = __builtin_amdgcn_mfma_f32_16x16x32_bf16(a.s, b.s, acc[ht], 0, 0, 0);
                }
            }
            if (c < 3) {
                *(uint4*)&lx[cur ^ 1][srow * LP + soff * 8]       = s0;
                *(uint4*)&lx[cur ^ 1][srow * LP + soff * 8 + 256] = s1;
            }
            __syncthreads();
            cur ^= 1;
        }
        #undef LDSEGF
    }

    // partials: C layout col = c16, row = g*4 + reg
    #pragma unroll
    for (int ht = 0; ht < 4; ++ht)
        #pragma unroll
        for (int r = 0; r < 4; ++r)
            red[w][g * 4 + r][ht * 16 + c16] = acc[ht][r];
    __syncthreads();

    // reduce 8 partials: 1024 cells, 512 threads x 2
    #pragma unroll
    for (int ii = 0; ii < 2; ++ii) {
        int idx = tid + ii * 512;
        int row = idx >> 6, h = idx & 63;
        float s = 0.0f;
        #pragma unroll
        for (int w2 = 0; w2 < 8; ++w2) s += red[w2][row][h];
        red[0][row][h] = s;
    }
    __syncthreads();

    if (tid < 16) {
        float h1v[NH1];
        #pragma unroll
        for (int h = 0; h < NH1; ++h) {
            float vv = red[0][tid][h] + Wmlp[500 + h];
            h1v[h] = vv >= 0.0f ? vv : 0.01f * vv;
        }
        float o = Wmlp[570];
        for (int j = 0; j < NH2; ++j) {
            float a2 = Wmlp[550 + j];
            #pragma unroll
            for (int h = 0; h < NH1; ++h)
                a2 = fmaf(h1v[h], Wmlp[h * NH2 + j], a2);
            a2 = a2 >= 0.0f ? a2 : 0.01f * a2;
            o = fmaf(a2, Wmlp[560 + j], o);
        }
        int b = r0 + tid;
        if (flag) ((unsigned short*)out)[b] = f2b(o);
        else      ((float*)out)[b] = o;
    }
}

extern "C" void kernel_launch(void* const* d_in, const int* in_sizes, int n_in,
                              void* d_out, int out_size, void* d_ws, size_t ws_size,
                              hipStream_t stream) {
    const void* x   = d_in[0];
    const void* raw = d_in[1];
    const void* W1  = d_in[2];
    const void* b1  = d_in[3];
    const void* W2  = d_in[4];
    const void* b2  = d_in[5];
    const void* W3  = d_in[6];
    const void* b3  = d_in[7];

    // Workspace: S_base 512 i32 | S_coef 17000 f32 | MB 65536 u32.
    // No atomics, no pre-zeroing; every read location written each launch
    // (m_build2 covers k2 0..1023 fully; MB zero-filled for k>=NB, h>=50).
    float* w      = (float*)d_ws;
    int*   S_base = (int*)w;                        // 512 ints
    float* S_coef = w + 512;                        // 17000 floats
    unsigned int* MB = (unsigned int*)(w + 17512);  // 65536 uints, 16B-aligned

    p1_stencil<<<8, 64, 0, stream>>>(x, raw, S_coef, S_base);
    m_build2<<<1024, 256, 0, stream>>>(x, W1, S_coef, S_base, MB);
    g_fused<<<512, 512, 0, stream>>>(x, MB, b1, W2, b2, W3, b3, d_out);
}